// Round 20
// baseline (157.884 us; speedup 1.0000x reference)
//
#include <hip/hip_runtime.h>
#include <hip/hip_bf16.h>

#define DEV __device__ __forceinline__

typedef unsigned char u8;
typedef unsigned short u16;
typedef unsigned int u32;
typedef long long i64;
typedef __attribute__((ext_vector_type(8))) short short8;
typedef __attribute__((ext_vector_type(4))) float f32x4;

DEV u16 f2bf(float f) {
  __hip_bfloat16 h = __float2bfloat16(f);   // RNE
  return *(u16*)&h;
}

#define NB 8
#define NH 6
#define CTOT 192
#define HW 16384
#define VTS 34     // k3 LDS n-row stride (u16): 17 dwords, coprime 32 banks
#define SLAB 2304  // kconv slab: 18 rows * 128 f32 (linear, global_load_lds dest)

// async global->LDS, 16B per lane, wave-uniform LDS base + lane*16
DEV void gload_lds(const float* src, float* dst) {
  __builtin_amdgcn_global_load_lds(
      (const __attribute__((address_space(1))) void*)src,
      (__attribute__((address_space(3))) void*)dst, 16, 0, 0);
}

// ---------------------------------------------------------------------------
// KCONV v9 (unchanged from R19 — best of 10 structural variants at ~95us):
// async double-buffered global_load_lds staging; block = (b, ch, 64-row
// half) computing q+k+v; 4 tiles of 16 rows; STAGE(t+1) issued before
// compute(t). q,k -> fp8 e4m3 + exact f32 norms; v -> bf16.
// ---------------------------------------------------------------------------
__global__ __launch_bounds__(256) void kconv(
    const float* __restrict__ x, const float* __restrict__ y,
    const float* __restrict__ wdw, const float* __restrict__ zp,
    u8* __restrict__ qws, u8* __restrict__ kws, u16* __restrict__ vws,
    float* __restrict__ sqq, float* __restrict__ sqk)
{
  __shared__ __align__(16) float bufX[2][SLAB];
  __shared__ __align__(16) float bufY[2][SLAB];
  const int t = threadIdx.x, lane = t & 63, w = t >> 6;
  const int bx   = blockIdx.x;          // 3072 = (b*192+gc)*2 + half
  const int half = bx & 1;
  const int task = bx >> 1;
  const int b  = task / 192;
  const int gc = task % 192;
  const int r0 = half * 64;

  const float* __restrict__ inx = x + (((size_t)(b * CTOT + gc)) << 14);
  const float* __restrict__ iny = y + (((size_t)(b * CTOT + gc)) << 14);

  float wq[9], wk[9], wv[9];
#pragma unroll
  for (int i = 0; i < 9; ++i) {
    wq[i] = wdw[gc * 9 + i];
    wk[i] = wdw[(CTOT + gc) * 9 + i];
    wv[i] = wdw[(2 * CTOT + gc) * 9 + i];
  }

  #define STAGE(bb, tt) { \
      const int tr0s = r0 + (tt) * 16; \
      const int px = (lane & 31) * 4; \
      for (int l = w; l < 9; l += 4) { \
        const int srow = tr0s - 1 + 2 * l + (lane >> 5); \
        const bool ok = (srow >= 0) && (srow < 128); \
        const float* sx = ok ? (inx + srow * 128 + px) : (zp + px); \
        const float* sy = ok ? (iny + srow * 128 + px) : (zp + px); \
        gload_lds(sx, &bufX[bb][l * 256]); \
        gload_lds(sy, &bufY[bb][l * 256]); \
      } }

  const int j   = t & 31;            // px group: px 4j..4j+3
  const int seg = t >> 5;            // 2-row segment 0..7 within tile

  u8*  __restrict__ qout = qws + (((size_t)(b * CTOT + gc)) << 14);
  u8*  __restrict__ kout = kws + (((size_t)(b * CTOT + gc)) << 14);
  u16* __restrict__ vout = vws + (((size_t)(b * CTOT + gc)) << 14);

  float ssq = 0.f, ssk = 0.f;

  #define RDROW(buf, ri, d) { \
      const float4 A = *(const float4*)&(buf)[(ri) * 128 + (j ? 4 * j - 4 : 0)]; \
      const float4 M = *(const float4*)&(buf)[(ri) * 128 + 4 * j]; \
      const float4 B = *(const float4*)&(buf)[(ri) * 128 + (j < 31 ? 4 * j + 4 : 124)]; \
      d[0] = j ? A.w : 0.f; \
      d[1] = M.x; d[2] = M.y; d[3] = M.z; d[4] = M.w; \
      d[5] = (j < 31) ? B.x : 0.f; }

  #define CONV4(Rw, wgt, k0, o0, o1, o2, o3) { \
      o0 = o1 = o2 = o3 = 0.f; \
      _Pragma("unroll") \
      for (int dr = 0; dr < 3; ++dr) { \
        const float* d = Rw[(k0) + dr]; \
        o0 = fmaf(wgt[dr * 3 + 0], d[0], o0); o0 = fmaf(wgt[dr * 3 + 1], d[1], o0); o0 = fmaf(wgt[dr * 3 + 2], d[2], o0); \
        o1 = fmaf(wgt[dr * 3 + 0], d[1], o1); o1 = fmaf(wgt[dr * 3 + 1], d[2], o1); o1 = fmaf(wgt[dr * 3 + 2], d[3], o1); \
        o2 = fmaf(wgt[dr * 3 + 0], d[2], o2); o2 = fmaf(wgt[dr * 3 + 1], d[3], o2); o2 = fmaf(wgt[dr * 3 + 2], d[4], o2); \
        o3 = fmaf(wgt[dr * 3 + 0], d[3], o3); o3 = fmaf(wgt[dr * 3 + 1], d[4], o3); o3 = fmaf(wgt[dr * 3 + 2], d[5], o3); \
      } }

  STAGE(0, 0);
  __syncthreads();

#pragma unroll
  for (int tt = 0; tt < 4; ++tt) {
    if (tt < 3) STAGE((tt + 1) & 1, tt + 1);     // async, drains under compute

    const int bb  = tt & 1;
    const int tr0 = r0 + tt * 16;

    float RX[4][6], RY[4][6];
#pragma unroll
    for (int i = 0; i < 4; ++i) {
      RDROW(bufX[bb], seg * 2 + i, RX[i]);
      RDROW(bufY[bb], seg * 2 + i, RY[i]);
    }

#pragma unroll
    for (int k = 0; k < 2; ++k) {
      const int r = tr0 + seg * 2 + k;
      float o0, o1, o2, o3;
      CONV4(RX, wq, k, o0, o1, o2, o3);
      ssq = fmaf(o0, o0, ssq); ssq = fmaf(o1, o1, ssq);
      ssq = fmaf(o2, o2, ssq); ssq = fmaf(o3, o3, ssq);
      u32 p = (u32)__builtin_amdgcn_cvt_pk_fp8_f32(o0, o1, 0, false);
      p = (u32)__builtin_amdgcn_cvt_pk_fp8_f32(o2, o3, (int)p, true);
      *(u32*)(qout + r * 128 + 4 * j) = p;
      CONV4(RY, wk, k, o0, o1, o2, o3);
      ssk = fmaf(o0, o0, ssk); ssk = fmaf(o1, o1, ssk);
      ssk = fmaf(o2, o2, ssk); ssk = fmaf(o3, o3, ssk);
      p = (u32)__builtin_amdgcn_cvt_pk_fp8_f32(o0, o1, 0, false);
      p = (u32)__builtin_amdgcn_cvt_pk_fp8_f32(o2, o3, (int)p, true);
      *(u32*)(kout + r * 128 + 4 * j) = p;
      CONV4(RY, wv, k, o0, o1, o2, o3);
      const u32 p01 = ((u32)f2bf(o1) << 16) | (u32)f2bf(o0);
      const u32 p23 = ((u32)f2bf(o3) << 16) | (u32)f2bf(o2);
      *(uint2*)(vout + r * 128 + 4 * j) = make_uint2(p01, p23);
    }
    __syncthreads();
  }
  #undef STAGE
  #undef RDROW
  #undef CONV4

  ssq += __shfl_xor(ssq, 1);  ssk += __shfl_xor(ssk, 1);
  ssq += __shfl_xor(ssq, 2);  ssk += __shfl_xor(ssk, 2);
  ssq += __shfl_xor(ssq, 4);  ssk += __shfl_xor(ssk, 4);
  ssq += __shfl_xor(ssq, 8);  ssk += __shfl_xor(ssk, 8);
  ssq += __shfl_xor(ssq, 16); ssk += __shfl_xor(ssk, 16);
  ssq += __shfl_xor(ssq, 32); ssk += __shfl_xor(ssk, 32);
  if (lane == 0) {
    atomicAdd(sqq + b * CTOT + gc, ssq);
    atomicAdd(sqk + b * CTOT + gc, ssk);
  }
}

// ---------------------------------------------------------------------------
// K2a (fp8) + XCD swizzle: blocks of one bh cluster on one XCD so its q/k
// panels (512KB) stay XCD-L2-resident across the 16 p-tiles. 768 % 8 == 0.
// ---------------------------------------------------------------------------
__global__ __launch_bounds__(256) void k2a_gram(
    const u8* __restrict__ qws, const u8* __restrict__ kws,
    float* __restrict__ gram)
{
  const int t = threadIdx.x, l = t & 63, w = t >> 6;
  const int swz = (blockIdx.x & 7) * 96 + (blockIdx.x >> 3);   // bijective, 768
  const int bh = swz >> 4, tile = swz & 15;
  const int p0 = tile * 1024 + w * 256;
  const u8* qb = qws + (((size_t)bh) << 19);   // bh * 32ch * 16384B
  const u8* kb = kws + (((size_t)bh) << 19);
  const int row = l & 15;
  const int kq  = (l >> 4) * 8;

  f32x4 acc[2][2] = {};

  for (int ks = 0; ks < 8; ++ks) {
    const int p = p0 + ks * 32 + kq;
    i64 av[2], bv[2];
#pragma unroll
    for (int tc = 0; tc < 2; ++tc) {
      av[tc] = *(const i64*)(qb + (((size_t)(tc * 16 + row)) << 14) + p);
      bv[tc] = *(const i64*)(kb + (((size_t)(tc * 16 + row)) << 14) + p);
    }
#pragma unroll
    for (int tc = 0; tc < 2; ++tc)
#pragma unroll
      for (int td = 0; td < 2; ++td)
        acc[tc][td] = __builtin_amdgcn_mfma_f32_16x16x32_fp8_fp8(av[tc], bv[td], acc[tc][td], 0, 0, 0);
  }

#pragma unroll
  for (int tc = 0; tc < 2; ++tc)
#pragma unroll
    for (int td = 0; td < 2; ++td)
#pragma unroll
      for (int rr = 0; rr < 4; ++rr) {
        int c = tc * 16 + (l >> 4) * 4 + rr;
        int d = td * 16 + row;
        atomicAdd(gram + (size_t)bh * 1024 + c * 32 + d, acc[tc][td][rr]);
      }
}

// ---------------------------------------------------------------------------
// K2b: logits = gram/(|q||k|)*temp, row-softmax, fold 1x1 proj:
//   W2[b][o][h*32+d] = sum_c wp[o][h*32+c] * A[c][d]  (bf16 out)
// ---------------------------------------------------------------------------
__global__ __launch_bounds__(256) void k2b_w2(
    const float* __restrict__ gram, const float* __restrict__ sqq,
    const float* __restrict__ sqk, const float* __restrict__ wp,
    const float* __restrict__ temp, u16* __restrict__ W2)
{
  __shared__ float Ls[32][33];
  __shared__ float As[32][33];
  __shared__ float wl[192 * 32];
  __shared__ float nq[32], nk[32];
  const int t = threadIdx.x;
  const int bh = blockIdx.x, b = bh / 6, h = bh % 6;
  const float tmp = temp[h];
  if (t < 32) nq[t] = fmaxf(sqrtf(sqq[b * CTOT + h * 32 + t]), 1e-12f);
  else if (t < 64) nk[t - 32] = fmaxf(sqrtf(sqk[b * CTOT + h * 32 + t - 32]), 1e-12f);
  __syncthreads();
#pragma unroll
  for (int i = 0; i < 4; ++i) {
    int idx = i * 256 + t, c = idx >> 5, d = idx & 31;
    Ls[c][d] = gram[(size_t)bh * 1024 + idx] / (nq[c] * nk[d]) * tmp;
  }
  __syncthreads();
  if (t < 32) {
    float m = -1e30f;
#pragma unroll
    for (int d = 0; d < 32; ++d) m = fmaxf(m, Ls[t][d]);
    float s = 0.f;
#pragma unroll
    for (int d = 0; d < 32; ++d) s += expf(Ls[t][d] - m);
    float inv = 1.0f / s;
#pragma unroll
    for (int d = 0; d < 32; ++d) As[t][d] = expf(Ls[t][d] - m) * inv;
  }
  for (int i = 0; i < 24; ++i) {
    int idx = i * 256 + t, o = idx >> 5, c = idx & 31;
    wl[idx] = wp[o * 192 + h * 32 + c];
  }
  __syncthreads();
  for (int i = 0; i < 24; ++i) {
    int idx = i * 256 + t, o = idx >> 5, d = idx & 31;
    float a = 0.f;
#pragma unroll
    for (int c = 0; c < 32; ++c) a = fmaf(wl[o * 32 + c], As[c][d], a);
    W2[((size_t)(b * 192 + o)) * 192 + h * 32 + d] = f2bf(a);
  }
}

// ---------------------------------------------------------------------------
// K3 + XCD swizzle: all 128 n-tiles of one batch cluster on one XCD, so that
// batch's W2 (73KB) is XCD-L2-resident and v/out streams have batch locality.
// 1024 % 8 == 0 -> bijective. v in natural [b][c][n]; per ks-step stage
// 32x128 tile -> LDS transpose; epilogue LDS-transpose for float4 out runs.
// ---------------------------------------------------------------------------
__global__ __launch_bounds__(256) void k3_gemm(
    const u16* __restrict__ W2, const u16* __restrict__ vnat,
    float* __restrict__ out)
{
  __shared__ __align__(16) u16 b_tile[128 * VTS];
  __shared__ __align__(16) float cout[32 * 132];
  const int t = threadIdx.x, l = t & 63, w = t >> 6;
  const int swz = (blockIdx.x & 7) * 128 + (blockIdx.x >> 3);  // bijective, 1024
  const int b  = swz >> 7, nb = swz & 127;
  const int arow = l & 15;
  const int kq8  = (l >> 4) * 8;
  const u16* w2b = W2 + (size_t)b * 192 * 192;
  const u16* vb  = vnat + ((size_t)b * CTOT) * HW;
  const int n0 = nb * 128;

  f32x4 acc[12][2] = {};

  for (int ks = 0; ks < 6; ++ks) {
    if (ks > 0) __syncthreads();
#pragma unroll
    for (int r2 = 0; r2 < 2; ++r2) {
      const int ch   = (t >> 4) + r2 * 16;
      const int nseg = (t & 15) * 8;
      short8 vv = *(const short8*)(vb + (size_t)(ks * 32 + ch) * HW + n0 + nseg);
#pragma unroll
      for (int j = 0; j < 8; ++j) b_tile[(nseg + j) * VTS + ch] = (u16)vv[j];
    }
    __syncthreads();

    short8 bf[2];
#pragma unroll
    for (int nt = 0; nt < 2; ++nt)
      bf[nt] = *(const short8*)&b_tile[(w * 32 + nt * 16 + arow) * VTS + kq8];
#pragma unroll
    for (int ot = 0; ot < 12; ++ot) {
      short8 af = *(const short8*)(w2b + (size_t)(ot * 16 + arow) * 192 + ks * 32 + kq8);
#pragma unroll
      for (int nt = 0; nt < 2; ++nt)
        acc[ot][nt] = __builtin_amdgcn_mfma_f32_16x16x32_bf16(af, bf[nt], acc[ot][nt], 0, 0, 0);
    }
  }

  float* __restrict__ ob = out + ((size_t)b * 192) * 16384;
#pragma unroll
  for (int og = 0; og < 6; ++og) {
    __syncthreads();
#pragma unroll
    for (int oi = 0; oi < 2; ++oi) {
#pragma unroll
      for (int nt = 0; nt < 2; ++nt)
#pragma unroll
        for (int rr = 0; rr < 4; ++rr) {
          const int o_l = oi * 16 + (l >> 4) * 4 + rr;
          const int n_l = w * 32 + nt * 16 + (l & 15);
          cout[o_l * 132 + n_l] = acc[og * 2 + oi][nt][rr];
        }
    }
    __syncthreads();
    const int o_l = t >> 3;
    const int o   = og * 32 + o_l;
#pragma unroll
    for (int c = 0; c < 4; ++c) {
      const int n = (t & 7) * 4 + c * 32;
      float4 v4;
      v4.x = cout[o_l * 132 + n + 0];
      v4.y = cout[o_l * 132 + n + 1];
      v4.z = cout[o_l * 132 + n + 2];
      v4.w = cout[o_l * 132 + n + 3];
      *(float4*)(ob + (size_t)o * 16384 + n0 + n) = v4;
    }
  }
}

// ---------------------------------------------------------------------------
extern "C" void kernel_launch(void* const* d_in, const int* in_sizes, int n_in,
                              void* d_out, int out_size, void* d_ws, size_t ws_size,
                              hipStream_t stream)
{
  const float* x    = (const float*)d_in[0];
  const float* y    = (const float*)d_in[1];
  const float* wdw  = (const float*)d_in[2];
  const float* wp   = (const float*)d_in[3];
  const float* temp = (const float*)d_in[4];

  char* ws = (char*)d_ws;
  const size_t QK8 = (size_t)NB * CTOT * HW;       // 25,165,824 B (fp8)
  const size_t VBF = (size_t)NB * CTOT * HW * 2;   // 50,331,648 B (bf16)
  u8*    qws  = (u8*)(ws);
  u8*    kws  = (u8*)(ws + QK8);
  u16*   vws  = (u16*)(ws + 2 * QK8);
  char*  meta = ws + 2 * QK8 + VBF;
  float* gram = (float*)(meta);                    // 196608 (also kconv zero page)
  float* sqq  = (float*)(meta + 196608);           // 6144
  float* sqk  = (float*)(meta + 196608 + 6144);    // 6144
  u16*   W2   = (u16*)(meta + 196608 + 12288);     // 8*192*192*2
  float* out  = (float*)d_out;

  hipMemsetAsync(meta, 0, 208896, stream);
  kconv<<<3072, 256, 0, stream>>>(x, y, wdw, gram, qws, kws, vws, sqq, sqk);
  k2a_gram<<<768, 256, 0, stream>>>(qws, kws, gram);
  k2b_w2<<<48, 256, 0, stream>>>(gram, sqq, sqk, wp, temp, W2);
  k3_gemm<<<1024, 256, 0, stream>>>(W2, vws, out);
}

// Round 21
// 153.960 us; speedup vs baseline: 1.0255x; 1.0255x over previous
//
#include <hip/hip_runtime.h>
#include <hip/hip_bf16.h>

#define DEV __device__ __forceinline__

typedef unsigned char u8;
typedef unsigned short u16;
typedef unsigned int u32;
typedef long long i64;
typedef __attribute__((ext_vector_type(8))) short short8;
typedef __attribute__((ext_vector_type(4))) float f32x4;

DEV u16 f2bf(float f) {
  __hip_bfloat16 h = __float2bfloat16(f);   // RNE
  return *(u16*)&h;
}

#define NB 8
#define NH 6
#define CTOT 192
#define HW 16384
#define VTS 34     // k3 LDS n-row stride (u16): 17 dwords, coprime 32 banks
#define SLAB 2304  // kconv slab: 18 rows * 128 f32 (linear, global_load_lds dest)

// async global->LDS, 16B per lane, wave-uniform LDS base + lane*16
DEV void gload_lds(const float* src, float* dst) {
  __builtin_amdgcn_global_load_lds(
      (const __attribute__((address_space(1))) void*)src,
      (__attribute__((address_space(3))) void*)dst, 16, 0, 0);
}

// ---------------------------------------------------------------------------
// KCONV v9 (R19 exact — best of 10 structural variants, ~93us):
// async double-buffered global_load_lds staging; block = (b, ch, 64-row
// half) computing q+k+v; 4 tiles of 16 rows; STAGE(t+1) issued before
// compute(t). q,k -> fp8 e4m3 + exact f32 norms; v -> bf16.
// ---------------------------------------------------------------------------
__global__ __launch_bounds__(256) void kconv(
    const float* __restrict__ x, const float* __restrict__ y,
    const float* __restrict__ wdw, const float* __restrict__ zp,
    u8* __restrict__ qws, u8* __restrict__ kws, u16* __restrict__ vws,
    float* __restrict__ sqq, float* __restrict__ sqk)
{
  __shared__ __align__(16) float bufX[2][SLAB];
  __shared__ __align__(16) float bufY[2][SLAB];
  const int t = threadIdx.x, lane = t & 63, w = t >> 6;
  const int bx   = blockIdx.x;          // 3072 = (b*192+gc)*2 + half
  const int half = bx & 1;
  const int task = bx >> 1;
  const int b  = task / 192;
  const int gc = task % 192;
  const int r0 = half * 64;

  const float* __restrict__ inx = x + (((size_t)(b * CTOT + gc)) << 14);
  const float* __restrict__ iny = y + (((size_t)(b * CTOT + gc)) << 14);

  float wq[9], wk[9], wv[9];
#pragma unroll
  for (int i = 0; i < 9; ++i) {
    wq[i] = wdw[gc * 9 + i];
    wk[i] = wdw[(CTOT + gc) * 9 + i];
    wv[i] = wdw[(2 * CTOT + gc) * 9 + i];
  }

  #define STAGE(bb, tt) { \
      const int tr0s = r0 + (tt) * 16; \
      const int px = (lane & 31) * 4; \
      for (int l = w; l < 9; l += 4) { \
        const int srow = tr0s - 1 + 2 * l + (lane >> 5); \
        const bool ok = (srow >= 0) && (srow < 128); \
        const float* sx = ok ? (inx + srow * 128 + px) : (zp + px); \
        const float* sy = ok ? (iny + srow * 128 + px) : (zp + px); \
        gload_lds(sx, &bufX[bb][l * 256]); \
        gload_lds(sy, &bufY[bb][l * 256]); \
      } }

  const int j   = t & 31;            // px group: px 4j..4j+3
  const int seg = t >> 5;            // 2-row segment 0..7 within tile

  u8*  __restrict__ qout = qws + (((size_t)(b * CTOT + gc)) << 14);
  u8*  __restrict__ kout = kws + (((size_t)(b * CTOT + gc)) << 14);
  u16* __restrict__ vout = vws + (((size_t)(b * CTOT + gc)) << 14);

  float ssq = 0.f, ssk = 0.f;

  #define RDROW(buf, ri, d) { \
      const float4 A = *(const float4*)&(buf)[(ri) * 128 + (j ? 4 * j - 4 : 0)]; \
      const float4 M = *(const float4*)&(buf)[(ri) * 128 + 4 * j]; \
      const float4 B = *(const float4*)&(buf)[(ri) * 128 + (j < 31 ? 4 * j + 4 : 124)]; \
      d[0] = j ? A.w : 0.f; \
      d[1] = M.x; d[2] = M.y; d[3] = M.z; d[4] = M.w; \
      d[5] = (j < 31) ? B.x : 0.f; }

  #define CONV4(Rw, wgt, k0, o0, o1, o2, o3) { \
      o0 = o1 = o2 = o3 = 0.f; \
      _Pragma("unroll") \
      for (int dr = 0; dr < 3; ++dr) { \
        const float* d = Rw[(k0) + dr]; \
        o0 = fmaf(wgt[dr * 3 + 0], d[0], o0); o0 = fmaf(wgt[dr * 3 + 1], d[1], o0); o0 = fmaf(wgt[dr * 3 + 2], d[2], o0); \
        o1 = fmaf(wgt[dr * 3 + 0], d[1], o1); o1 = fmaf(wgt[dr * 3 + 1], d[2], o1); o1 = fmaf(wgt[dr * 3 + 2], d[3], o1); \
        o2 = fmaf(wgt[dr * 3 + 0], d[2], o2); o2 = fmaf(wgt[dr * 3 + 1], d[3], o2); o2 = fmaf(wgt[dr * 3 + 2], d[4], o2); \
        o3 = fmaf(wgt[dr * 3 + 0], d[3], o3); o3 = fmaf(wgt[dr * 3 + 1], d[4], o3); o3 = fmaf(wgt[dr * 3 + 2], d[5], o3); \
      } }

  STAGE(0, 0);
  __syncthreads();

#pragma unroll
  for (int tt = 0; tt < 4; ++tt) {
    if (tt < 3) STAGE((tt + 1) & 1, tt + 1);     // async, drains under compute

    const int bb  = tt & 1;
    const int tr0 = r0 + tt * 16;

    float RX[4][6], RY[4][6];
#pragma unroll
    for (int i = 0; i < 4; ++i) {
      RDROW(bufX[bb], seg * 2 + i, RX[i]);
      RDROW(bufY[bb], seg * 2 + i, RY[i]);
    }

#pragma unroll
    for (int k = 0; k < 2; ++k) {
      const int r = tr0 + seg * 2 + k;
      float o0, o1, o2, o3;
      CONV4(RX, wq, k, o0, o1, o2, o3);
      ssq = fmaf(o0, o0, ssq); ssq = fmaf(o1, o1, ssq);
      ssq = fmaf(o2, o2, ssq); ssq = fmaf(o3, o3, ssq);
      u32 p = (u32)__builtin_amdgcn_cvt_pk_fp8_f32(o0, o1, 0, false);
      p = (u32)__builtin_amdgcn_cvt_pk_fp8_f32(o2, o3, (int)p, true);
      *(u32*)(qout + r * 128 + 4 * j) = p;
      CONV4(RY, wk, k, o0, o1, o2, o3);
      ssk = fmaf(o0, o0, ssk); ssk = fmaf(o1, o1, ssk);
      ssk = fmaf(o2, o2, ssk); ssk = fmaf(o3, o3, ssk);
      p = (u32)__builtin_amdgcn_cvt_pk_fp8_f32(o0, o1, 0, false);
      p = (u32)__builtin_amdgcn_cvt_pk_fp8_f32(o2, o3, (int)p, true);
      *(u32*)(kout + r * 128 + 4 * j) = p;
      CONV4(RY, wv, k, o0, o1, o2, o3);
      const u32 p01 = ((u32)f2bf(o1) << 16) | (u32)f2bf(o0);
      const u32 p23 = ((u32)f2bf(o3) << 16) | (u32)f2bf(o2);
      *(uint2*)(vout + r * 128 + 4 * j) = make_uint2(p01, p23);
    }
    __syncthreads();
  }
  #undef STAGE
  #undef RDROW
  #undef CONV4

  ssq += __shfl_xor(ssq, 1);  ssk += __shfl_xor(ssk, 1);
  ssq += __shfl_xor(ssq, 2);  ssk += __shfl_xor(ssk, 2);
  ssq += __shfl_xor(ssq, 4);  ssk += __shfl_xor(ssk, 4);
  ssq += __shfl_xor(ssq, 8);  ssk += __shfl_xor(ssk, 8);
  ssq += __shfl_xor(ssq, 16); ssk += __shfl_xor(ssk, 16);
  ssq += __shfl_xor(ssq, 32); ssk += __shfl_xor(ssk, 32);
  if (lane == 0) {
    atomicAdd(sqq + b * CTOT + gc, ssq);
    atomicAdd(sqk + b * CTOT + gc, ssk);
  }
}

// ---------------------------------------------------------------------------
// K2a (fp8): per (b,head) gram[c][d] = sum_n q[c][n]*k[d][n] via
// mfma_f32_16x16x32_fp8_fp8 (i64 fragments = 8 fp8/lane).
// grid 48x16 p-tiles, f32-atomic partials (pre-zeroed). No swizzle (R20: T1
// was neutral-to-harmful here — natural dispatch already bh-local).
// ---------------------------------------------------------------------------
__global__ __launch_bounds__(256) void k2a_gram(
    const u8* __restrict__ qws, const u8* __restrict__ kws,
    float* __restrict__ gram)
{
  const int t = threadIdx.x, l = t & 63, w = t >> 6;
  const int bh = blockIdx.x >> 4, tile = blockIdx.x & 15;
  const int p0 = tile * 1024 + w * 256;
  const u8* qb = qws + (((size_t)bh) << 19);   // bh * 32ch * 16384B
  const u8* kb = kws + (((size_t)bh) << 19);
  const int row = l & 15;
  const int kq  = (l >> 4) * 8;

  f32x4 acc[2][2] = {};

  for (int ks = 0; ks < 8; ++ks) {
    const int p = p0 + ks * 32 + kq;
    i64 av[2], bv[2];
#pragma unroll
    for (int tc = 0; tc < 2; ++tc) {
      av[tc] = *(const i64*)(qb + (((size_t)(tc * 16 + row)) << 14) + p);
      bv[tc] = *(const i64*)(kb + (((size_t)(tc * 16 + row)) << 14) + p);
    }
#pragma unroll
    for (int tc = 0; tc < 2; ++tc)
#pragma unroll
      for (int td = 0; td < 2; ++td)
        acc[tc][td] = __builtin_amdgcn_mfma_f32_16x16x32_fp8_fp8(av[tc], bv[td], acc[tc][td], 0, 0, 0);
  }

#pragma unroll
  for (int tc = 0; tc < 2; ++tc)
#pragma unroll
    for (int td = 0; td < 2; ++td)
#pragma unroll
      for (int rr = 0; rr < 4; ++rr) {
        int c = tc * 16 + (l >> 4) * 4 + rr;
        int d = td * 16 + row;
        atomicAdd(gram + (size_t)bh * 1024 + c * 32 + d, acc[tc][td][rr]);
      }
}

// ---------------------------------------------------------------------------
// K2b: logits = gram/(|q||k|)*temp, row-softmax, fold 1x1 proj:
//   W2[b][o][h*32+d] = sum_c wp[o][h*32+c] * A[c][d]  (bf16 out)
// ---------------------------------------------------------------------------
__global__ __launch_bounds__(256) void k2b_w2(
    const float* __restrict__ gram, const float* __restrict__ sqq,
    const float* __restrict__ sqk, const float* __restrict__ wp,
    const float* __restrict__ temp, u16* __restrict__ W2)
{
  __shared__ float Ls[32][33];
  __shared__ float As[32][33];
  __shared__ float wl[192 * 32];
  __shared__ float nq[32], nk[32];
  const int t = threadIdx.x;
  const int bh = blockIdx.x, b = bh / 6, h = bh % 6;
  const float tmp = temp[h];
  if (t < 32) nq[t] = fmaxf(sqrtf(sqq[b * CTOT + h * 32 + t]), 1e-12f);
  else if (t < 64) nk[t - 32] = fmaxf(sqrtf(sqk[b * CTOT + h * 32 + t - 32]), 1e-12f);
  __syncthreads();
#pragma unroll
  for (int i = 0; i < 4; ++i) {
    int idx = i * 256 + t, c = idx >> 5, d = idx & 31;
    Ls[c][d] = gram[(size_t)bh * 1024 + idx] / (nq[c] * nk[d]) * tmp;
  }
  __syncthreads();
  if (t < 32) {
    float m = -1e30f;
#pragma unroll
    for (int d = 0; d < 32; ++d) m = fmaxf(m, Ls[t][d]);
    float s = 0.f;
#pragma unroll
    for (int d = 0; d < 32; ++d) s += expf(Ls[t][d] - m);
    float inv = 1.0f / s;
#pragma unroll
    for (int d = 0; d < 32; ++d) As[t][d] = expf(Ls[t][d] - m) * inv;
  }
  for (int i = 0; i < 24; ++i) {
    int idx = i * 256 + t, o = idx >> 5, c = idx & 31;
    wl[idx] = wp[o * 192 + h * 32 + c];
  }
  __syncthreads();
  for (int i = 0; i < 24; ++i) {
    int idx = i * 256 + t, o = idx >> 5, d = idx & 31;
    float a = 0.f;
#pragma unroll
    for (int c = 0; c < 32; ++c) a = fmaf(wl[o * 32 + c], As[c][d], a);
    W2[((size_t)(b * 192 + o)) * 192 + h * 32 + d] = f2bf(a);
  }
}

// ---------------------------------------------------------------------------
// K3: out[b][o][n] = sum_c W2[b][o][c] * v[b][c][n], MFMA 16x16x32 bf16.
// v in natural [b][c][n]; per ks-step stage 32x128 tile -> LDS transpose.
// Epilogue: LDS-transpose C so global stores are contiguous float4 runs.
// No swizzle (R20: concentrating one batch's out-writes per XCD hurt).
// ---------------------------------------------------------------------------
__global__ __launch_bounds__(256) void k3_gemm(
    const u16* __restrict__ W2, const u16* __restrict__ vnat,
    float* __restrict__ out)
{
  __shared__ __align__(16) u16 b_tile[128 * VTS];
  __shared__ __align__(16) float cout[32 * 132];
  const int t = threadIdx.x, l = t & 63, w = t >> 6;
  const int bx = blockIdx.x;
  const int b  = bx >> 7, nb = bx & 127;
  const int arow = l & 15;
  const int kq8  = (l >> 4) * 8;
  const u16* w2b = W2 + (size_t)b * 192 * 192;
  const u16* vb  = vnat + ((size_t)b * CTOT) * HW;
  const int n0 = nb * 128;

  f32x4 acc[12][2] = {};

  for (int ks = 0; ks < 6; ++ks) {
    if (ks > 0) __syncthreads();
#pragma unroll
    for (int r2 = 0; r2 < 2; ++r2) {
      const int ch   = (t >> 4) + r2 * 16;
      const int nseg = (t & 15) * 8;
      short8 vv = *(const short8*)(vb + (size_t)(ks * 32 + ch) * HW + n0 + nseg);
#pragma unroll
      for (int j = 0; j < 8; ++j) b_tile[(nseg + j) * VTS + ch] = (u16)vv[j];
    }
    __syncthreads();

    short8 bf[2];
#pragma unroll
    for (int nt = 0; nt < 2; ++nt)
      bf[nt] = *(const short8*)&b_tile[(w * 32 + nt * 16 + arow) * VTS + kq8];
#pragma unroll
    for (int ot = 0; ot < 12; ++ot) {
      short8 af = *(const short8*)(w2b + (size_t)(ot * 16 + arow) * 192 + ks * 32 + kq8);
#pragma unroll
      for (int nt = 0; nt < 2; ++nt)
        acc[ot][nt] = __builtin_amdgcn_mfma_f32_16x16x32_bf16(af, bf[nt], acc[ot][nt], 0, 0, 0);
    }
  }

  float* __restrict__ ob = out + ((size_t)b * 192) * 16384;
#pragma unroll
  for (int og = 0; og < 6; ++og) {
    __syncthreads();
#pragma unroll
    for (int oi = 0; oi < 2; ++oi) {
#pragma unroll
      for (int nt = 0; nt < 2; ++nt)
#pragma unroll
        for (int rr = 0; rr < 4; ++rr) {
          const int o_l = oi * 16 + (l >> 4) * 4 + rr;
          const int n_l = w * 32 + nt * 16 + (l & 15);
          cout[o_l * 132 + n_l] = acc[og * 2 + oi][nt][rr];
        }
    }
    __syncthreads();
    const int o_l = t >> 3;
    const int o   = og * 32 + o_l;
#pragma unroll
    for (int c = 0; c < 4; ++c) {
      const int n = (t & 7) * 4 + c * 32;
      float4 v4;
      v4.x = cout[o_l * 132 + n + 0];
      v4.y = cout[o_l * 132 + n + 1];
      v4.z = cout[o_l * 132 + n + 2];
      v4.w = cout[o_l * 132 + n + 3];
      *(float4*)(ob + (size_t)o * 16384 + n0 + n) = v4;
    }
  }
}

// ---------------------------------------------------------------------------
extern "C" void kernel_launch(void* const* d_in, const int* in_sizes, int n_in,
                              void* d_out, int out_size, void* d_ws, size_t ws_size,
                              hipStream_t stream)
{
  const float* x    = (const float*)d_in[0];
  const float* y    = (const float*)d_in[1];
  const float* wdw  = (const float*)d_in[2];
  const float* wp   = (const float*)d_in[3];
  const float* temp = (const float*)d_in[4];

  char* ws = (char*)d_ws;
  const size_t QK8 = (size_t)NB * CTOT * HW;       // 25,165,824 B (fp8)
  const size_t VBF = (size_t)NB * CTOT * HW * 2;   // 50,331,648 B (bf16)
  u8*    qws  = (u8*)(ws);
  u8*    kws  = (u8*)(ws + QK8);
  u16*   vws  = (u16*)(ws + 2 * QK8);
  char*  meta = ws + 2 * QK8 + VBF;
  float* gram = (float*)(meta);                    // 196608 (also kconv zero page)
  float* sqq  = (float*)(meta + 196608);           // 6144
  float* sqk  = (float*)(meta + 196608 + 6144);    // 6144
  u16*   W2   = (u16*)(meta + 196608 + 12288);     // 8*192*192*2
  float* out  = (float*)d_out;

  hipMemsetAsync(meta, 0, 208896, stream);
  kconv<<<3072, 256, 0, stream>>>(x, y, wdw, gram, qws, kws, vws, sqq, sqk);
  k2a_gram<<<768, 256, 0, stream>>>(qws, kws, gram);
  k2b_w2<<<48, 256, 0, stream>>>(gram, sqq, sqk, wp, temp, W2);
  k3_gemm<<<1024, 256, 0, stream>>>(W2, vws, out);
}